// Round 7
// baseline (477.308 us; speedup 1.0000x reference)
//
#include <hip/hip_runtime.h>
#include <math.h>

#define H  14
#define C  7
#define HC 98
#define FIN 256
#define NEG_SLOPE 0.2f
#define NPB 32
#define AGG_BLOCK (NPB * H)   // 448 = 7 full waves

#define BSHIFT 7
#define BSIZE  128
#define NBUCK_MAX 1024
#define DBINS 64

typedef __attribute__((ext_vector_type(8))) short short8;
typedef __attribute__((ext_vector_type(4))) float floatx4;

#define WT_ROWS   112            // 98 cols zero-padded to 7*16
#define WT_STRIDE 264            // 256 + 8 pad (bf16 units)
#define XA_STRIDE 40             // 32 + 8 pad (bf16 units)

// f32 -> bf16 bits, round-to-nearest-even
__device__ __forceinline__ unsigned bf16r(float f) {
    unsigned u = __float_as_uint(f);
    return (u + 0x7FFFu + ((u >> 16) & 1u)) >> 16;
}
__device__ __forceinline__ float bflo(unsigned w) { return __uint_as_float(w << 16); }
__device__ __forceinline__ float bfhi(unsigned w) { return __uint_as_float(w & 0xFFFF0000u); }

// ---------------- bucketed CSR construction (no self loops) ----------------

__global__ void k_zero(int* __restrict__ p, int n) {
    int i = blockIdx.x * blockDim.x + threadIdx.x;
    if (i < n) p[i] = 0;
}

__global__ __launch_bounds__(256) void k_hist(const int* __restrict__ ei, int E,
                                              int* __restrict__ gcnt, int nb) {
    __shared__ int hist[NBUCK_MAX];
    const int t = threadIdx.x;
    for (int i = t; i < nb; i += 256) hist[i] = 0;
    __syncthreads();
    const int stride = gridDim.x * 256;
    for (int e = blockIdx.x * 256 + t; e < E; e += stride)
        atomicAdd(&hist[ei[E + e] >> BSHIFT], 1);
    __syncthreads();
    for (int i = t; i < nb; i += 256)
        if (hist[i]) atomicAdd(gcnt + i, hist[i]);
}

__global__ __launch_bounds__(1024) void k_bscan(const int* __restrict__ gcnt,
                                                int* __restrict__ boff, int* __restrict__ bcur,
                                                int* __restrict__ row_ptr, int nb, int N) {
    __shared__ int sd[1024];
    int t = threadIdx.x;
    int own = (t < nb) ? gcnt[t] : 0;
    sd[t] = own;
    __syncthreads();
    #pragma unroll
    for (int off = 1; off < 1024; off <<= 1) {
        int v = (t >= off) ? sd[t - off] : 0;
        __syncthreads();
        sd[t] += v;
        __syncthreads();
    }
    if (t < nb) {
        boff[t + 1] = sd[t];
        bcur[t] = sd[t] - own;          // exclusive
        if (t == nb - 1) row_ptr[N] = sd[t];
    }
    if (t == 0) boff[0] = 0;
}

__global__ __launch_bounds__(256) void k_part(const int* __restrict__ ei, int E,
                                              int* __restrict__ bcur, int2* __restrict__ pedge,
                                              int nb) {
    __shared__ int hist[NBUCK_MAX];
    __shared__ int start[NBUCK_MAX];
    const int t = threadIdx.x;
    const int chunk = (E + gridDim.x - 1) / gridDim.x;
    const int c0 = blockIdx.x * chunk;
    const int c1 = min(c0 + chunk, E);
    for (int i = t; i < nb; i += 256) hist[i] = 0;
    __syncthreads();
    for (int e = c0 + t; e < c1; e += 256)
        atomicAdd(&hist[ei[E + e] >> BSHIFT], 1);
    __syncthreads();
    for (int i = t; i < nb; i += 256) {
        int h = hist[i];
        start[i] = h ? atomicAdd(bcur + i, h) : 0;
        hist[i] = 0;                     // reuse as local cursor
    }
    __syncthreads();
    for (int e = c0 + t; e < c1; e += 256) {
        int s = ei[e], d = ei[E + e];
        int b = d >> BSHIFT;
        int pos = start[b] + atomicAdd(&hist[b], 1);
        pedge[pos] = make_int2(s, d);
    }
}

__global__ __launch_bounds__(256) void k_bcsr(const int2* __restrict__ pedge,
                                              const int* __restrict__ boff,
                                              int* __restrict__ row_ptr, int* __restrict__ col,
                                              int N) {
    __shared__ int cnt[BSIZE];
    __shared__ int sc[BSIZE];
    __shared__ int cur[BSIZE];
    const int b  = blockIdx.x;
    const int t  = threadIdx.x;
    const int e0 = boff[b], e1 = boff[b + 1];
    const int base = b << BSHIFT;
    const int nv = min(BSIZE, N - base);
    if (t < BSIZE) cnt[t] = 0;
    __syncthreads();
    for (int e = e0 + t; e < e1; e += 256)
        atomicAdd(&cnt[pedge[e].y - base], 1);
    __syncthreads();
    if (t < BSIZE) sc[t] = cnt[t];
    __syncthreads();
    #pragma unroll
    for (int off = 1; off < BSIZE; off <<= 1) {
        int v = 0;
        if (t < BSIZE && t >= off) v = sc[t - off];
        __syncthreads();
        if (t < BSIZE) sc[t] += v;
        __syncthreads();
    }
    if (t < nv) {
        int excl = sc[t] - cnt[t];
        row_ptr[base + t] = e0 + excl;
        cur[t] = excl;
    }
    __syncthreads();
    for (int e = e0 + t; e < e1; e += 256) {
        int2 r = pedge[e];
        int d = r.y - base;
        int pos = e0 + atomicAdd(&cur[d], 1);
        col[pos] = r.x;
    }
}

// ---------------- degree-sorted node permutation ----------------

__global__ __launch_bounds__(256) void k_dhist(const int* __restrict__ row_ptr,
                                               int* __restrict__ dcnt, int N) {
    __shared__ int hist[DBINS];
    const int t = threadIdx.x;
    if (t < DBINS) hist[t] = 0;
    __syncthreads();
    int n = blockIdx.x * 256 + t;
    if (n < N) {
        int bin = min(row_ptr[n + 1] - row_ptr[n], DBINS - 1);
        atomicAdd(&hist[bin], 1);
    }
    __syncthreads();
    if (t < DBINS && hist[t]) atomicAdd(dcnt + t, hist[t]);
}

__global__ void k_dscan(const int* __restrict__ dcnt, int* __restrict__ dcur) {
    if (threadIdx.x == 0) {
        int acc = 0;
        for (int b = 0; b < DBINS; ++b) { dcur[b] = acc; acc += dcnt[b]; }
    }
}

__global__ __launch_bounds__(256) void k_dperm(const int* __restrict__ row_ptr,
                                               int* __restrict__ dcur, int* __restrict__ perm,
                                               int N) {
    __shared__ int hist[DBINS];
    __shared__ int start[DBINS];
    const int t = threadIdx.x;
    if (t < DBINS) hist[t] = 0;
    __syncthreads();
    int n = blockIdx.x * 256 + t;
    int bin = -1;
    if (n < N) {
        bin = min(row_ptr[n + 1] - row_ptr[n], DBINS - 1);
        atomicAdd(&hist[bin], 1);
    }
    __syncthreads();
    if (t < DBINS) {
        int h = hist[t];
        start[t] = h ? atomicAdd(dcur + t, h) : 0;
        hist[t] = 0;
    }
    __syncthreads();
    if (n < N) {
        int pos = start[bin] + atomicAdd(&hist[bin], 1);
        perm[pos] = n;
    }
}

// ---------------- layer-1 projection via MFMA ----------------

__global__ void k_convW(const float* __restrict__ W, unsigned short* __restrict__ WtG) {
    int id = blockIdx.x * blockDim.x + threadIdx.x;   // 112*256
    int n = id >> 8, k = id & 255;
    float v = (n < HC) ? W[k * HC + n] : 0.f;
    WtG[id] = (unsigned short)(__float_as_uint(v) >> 16);  // exact: inputs bf16-rounded
}

__global__ __launch_bounds__(256) void k_proj1_mfma(
    const float* __restrict__ x, const unsigned short* __restrict__ WtG,
    unsigned short* __restrict__ xhb, int N)
{
    __shared__ unsigned short wt_s[WT_ROWS * WT_STRIDE];  // 59136 B
    __shared__ unsigned short xa_s[64 * XA_STRIDE];       //  5120 B
    const int t  = threadIdx.x;
    const int wv = t >> 6;
    const int l  = t & 63;
    const int ln = l & 15;
    const int qd = l >> 4;
    const int rowBase = blockIdx.x * 64;

    #pragma unroll
    for (int i = 0; i < 14; ++i) {
        int f = i * 256 + t;            // uint4 index, 3584 total (32 per row)
        int r = f >> 5, pos = f & 31;
        *(uint4*)(wt_s + r * WT_STRIDE + pos * 8) = ((const uint4*)WtG)[f];
    }

    floatx4 acc[7] = {};

    for (int step = 0; step < 8; ++step) {
        const int k0 = step * 32;
        __syncthreads();
        #pragma unroll
        for (int i = 0; i < 2; ++i) {
            int idx = i * 256 + t;       // 512 float4 total
            int r = idx >> 3, c4 = idx & 7;
            int gr = rowBase + r; if (gr >= N) gr = N - 1;
            float4 v = *(const float4*)(x + (size_t)gr * FIN + k0 + c4 * 4);
            ushort4 u;
            u.x = (unsigned short)(__float_as_uint(v.x) >> 16);
            u.y = (unsigned short)(__float_as_uint(v.y) >> 16);
            u.z = (unsigned short)(__float_as_uint(v.z) >> 16);
            u.w = (unsigned short)(__float_as_uint(v.w) >> 16);
            *(ushort4*)(xa_s + r * XA_STRIDE + c4 * 4) = u;
        }
        __syncthreads();
        short8 a = *(const short8*)(xa_s + ((wv << 4) + ln) * XA_STRIDE + qd * 8);
        #pragma unroll
        for (int ct = 0; ct < 7; ++ct) {
            short8 b = *(const short8*)(wt_s + (ct * 16 + ln) * WT_STRIDE + k0 + qd * 8);
            acc[ct] = __builtin_amdgcn_mfma_f32_16x16x32_bf16(a, b, acc[ct], 0, 0, 0);
        }
    }

    // C/D: col = ln, row = qd*4 + r
    #pragma unroll
    for (int ct = 0; ct < 7; ++ct) {
        #pragma unroll
        for (int r = 0; r < 4; ++r) {
            int gr   = rowBase + (wv << 4) + (qd << 2) + r;
            int colg = ct * 16 + ln;
            if (gr < N && colg < HC)
                xhb[(size_t)gr * HC + colg] = (unsigned short)bf16r(acc[ct][r]);
        }
    }
}

// layer-1 pack: per (n,h) build 16B record {7 msg bf16, src-logit bf16} + aldst f32
__global__ void k_pack1(const unsigned short* __restrict__ xhb,
                        const float* __restrict__ asrc, const float* __restrict__ adst,
                        uint4* __restrict__ xpack, float* __restrict__ aldst, int NH)
{
    int id = blockIdx.x * blockDim.x + threadIdx.x;
    if (id >= NH) return;
    int n = id / H, h = id - n * H;
    const unsigned short* xp = xhb + (size_t)n * HC + h * C;
    unsigned v[C];
    float s1 = 0.f, s2 = 0.f;
    #pragma unroll
    for (int c2 = 0; c2 < C; ++c2) {
        v[c2] = xp[c2];
        float f = bflo(v[c2]);
        s1 = fmaf(f, asrc[h * C + c2], s1);
        s2 = fmaf(f, adst[h * C + c2], s2);
    }
    uint4 pk;
    pk.x = v[0] | (v[1] << 16);
    pk.y = v[2] | (v[3] << 16);
    pk.z = v[4] | (v[5] << 16);
    pk.w = v[6] | (bf16r(s1) << 16);
    xpack[id] = pk;
    aldst[id] = s2;
}

// ---------------- layer-2 projection + pack (thread per node) ----------------

__global__ __launch_bounds__(256) void k_proj2_pack(
    const float* __restrict__ h1, const float* __restrict__ W,
    const float* __restrict__ asrc, const float* __restrict__ adst,
    uint4* __restrict__ xpack, float* __restrict__ aldst, int N)
{
    __shared__ float Ws[C * HC];
    __shared__ float as_s[HC], ad_s[HC];
    const int t = threadIdx.x;
    for (int i = t; i < C * HC; i += 256) Ws[i] = W[i];
    if (t < HC) { as_s[t] = asrc[t]; ad_s[t] = adst[t]; }
    __syncthreads();
    int n = blockIdx.x * 256 + t;
    if (n >= N) return;
    float xr[C];
    #pragma unroll
    for (int c2 = 0; c2 < C; ++c2) xr[c2] = h1[(size_t)n * C + c2];
    #pragma unroll
    for (int h = 0; h < H; ++h) {
        float v[C], s1 = 0.f, s2 = 0.f;
        #pragma unroll
        for (int c2 = 0; c2 < C; ++c2) {
            float acc = 0.f;
            #pragma unroll
            for (int k = 0; k < C; ++k)
                acc = fmaf(xr[k], Ws[k * HC + h * C + c2], acc);
            v[c2] = acc;
            s1 = fmaf(acc, as_s[h * C + c2], s1);
            s2 = fmaf(acc, ad_s[h * C + c2], s2);
        }
        uint4 pk;
        pk.x = bf16r(v[0]) | (bf16r(v[1]) << 16);
        pk.y = bf16r(v[2]) | (bf16r(v[3]) << 16);
        pk.z = bf16r(v[4]) | (bf16r(v[5]) << 16);
        pk.w = bf16r(v[6]) | (bf16r(s1) << 16);
        xpack[(size_t)n * H + h] = pk;
        aldst[(size_t)n * H + h] = s2;
    }
}

// ---------------- fused aggregation ----------------
// thread = (perm-node, head); self-loop initializes state; depth-4 prefetch

template<int LAYER>
__global__ __launch_bounds__(AGG_BLOCK) void k_agg(
    const int* __restrict__ perm,
    const int* __restrict__ row_ptr, const int* __restrict__ col,
    const uint4* __restrict__ xpack, const float* __restrict__ aldst,
    const float* __restrict__ bias,
    float* __restrict__ h1, float* __restrict__ out, int N)
{
    __shared__ float vals[NPB][HC];
    __shared__ float fv[NPB][C];
    __shared__ int pn[NPB];
    const int t  = threadIdx.x;
    const int nl = t / H;
    const int h  = t - nl * H;
    if (t < NPB) {
        int idx = blockIdx.x * NPB + t;
        pn[t] = (idx < N) ? perm[idx] : -1;
    }
    __syncthreads();
    const int n = pn[nl];

    if (n >= 0) {
        const int e0  = row_ptr[n];
        const int deg = row_ptr[n + 1] - e0;
        const float ld = aldst[(size_t)n * H + h];
        float m, den, mx[C];
        {   // self loop (implicit)
            uint4 pk = xpack[(size_t)n * H + h];
            float l = bfhi(pk.w) + ld;
            l = (l > 0.f) ? l : NEG_SLOPE * l;
            m = l; den = 1.f;
            mx[0] = bflo(pk.x); mx[1] = bfhi(pk.x);
            mx[2] = bflo(pk.y); mx[3] = bfhi(pk.y);
            mx[4] = bflo(pk.z); mx[5] = bfhi(pk.z);
            mx[6] = bflo(pk.w);
        }
        // depth-4 rolling prefetch
        uint4 b0, b1, b2, b3;
        if (deg > 0) b0 = xpack[(size_t)col[e0]     * H + h];
        if (deg > 1) b1 = xpack[(size_t)col[e0 + 1] * H + h];
        if (deg > 2) b2 = xpack[(size_t)col[e0 + 2] * H + h];
        if (deg > 3) b3 = xpack[(size_t)col[e0 + 3] * H + h];
        for (int i = 0; i < deg; ++i) {
            uint4 cur = b0;
            b0 = b1; b1 = b2; b2 = b3;
            if (i + 4 < deg) b3 = xpack[(size_t)col[e0 + i + 4] * H + h];
            float l = bfhi(cur.w) + ld;
            l = (l > 0.f) ? l : NEG_SLOPE * l;
            float mn = fmaxf(m, l);
            float r  = __expf(m - mn);
            float p  = __expf(l - mn);
            den = den * r + p;
            mx[0] = fmaxf(mx[0] * r, p * bflo(cur.x));
            mx[1] = fmaxf(mx[1] * r, p * bfhi(cur.x));
            mx[2] = fmaxf(mx[2] * r, p * bflo(cur.y));
            mx[3] = fmaxf(mx[3] * r, p * bfhi(cur.y));
            mx[4] = fmaxf(mx[4] * r, p * bflo(cur.z));
            mx[5] = fmaxf(mx[5] * r, p * bfhi(cur.z));
            mx[6] = fmaxf(mx[6] * r, p * bflo(cur.w));
            m = mn;
        }
        float rd = 1.f / den;
        #pragma unroll
        for (int c2 = 0; c2 < C; ++c2) vals[nl][h * C + c2] = mx[c2] * rd;
    }
    __syncthreads();

    if (t < NPB * C) {
        int nl2 = t / C, c2 = t - nl2 * C;
        int n2 = pn[nl2];
        if (n2 >= 0) {
            float s = 0.f;
            #pragma unroll
            for (int hh = 0; hh < H; ++hh) s += vals[nl2][hh * C + c2];
            float o = s * (1.f / H) + bias[c2];
            if (LAYER == 1) h1[(size_t)n2 * C + c2] = fmaxf(o, 0.f);
            else            fv[nl2][c2] = o;
        }
    }
    if (LAYER == 2) {
        __syncthreads();
        if (t < NPB) {
            int n2 = pn[t];
            if (n2 >= 0) {
                float mv = -1e30f;
                #pragma unroll
                for (int c2 = 0; c2 < C; ++c2) mv = fmaxf(mv, fv[t][c2]);
                float lse = 0.f;
                #pragma unroll
                for (int c2 = 0; c2 < C; ++c2) lse += __expf(fv[t][c2] - mv);
                lse = logf(lse);
                #pragma unroll
                for (int c2 = 0; c2 < C; ++c2)
                    out[(size_t)n2 * C + c2] = fv[t][c2] - mv - lse;
            }
        }
    }
}

// ---------------- launch ----------------

static inline size_t align16(size_t v) { return (v + 15) & ~(size_t)15; }

extern "C" void kernel_launch(void* const* d_in, const int* in_sizes, int n_in,
                              void* d_out, int out_size, void* d_ws, size_t ws_size,
                              hipStream_t stream)
{
    const float* x     = (const float*)d_in[0];
    const int*   ei    = (const int*)d_in[1];
    const float* W1    = (const float*)d_in[2];
    const float* asrc1 = (const float*)d_in[3];
    const float* adst1 = (const float*)d_in[4];
    const float* b1    = (const float*)d_in[5];
    const float* W2    = (const float*)d_in[6];
    const float* asrc2 = (const float*)d_in[7];
    const float* adst2 = (const float*)d_in[8];
    const float* b2    = (const float*)d_in[9];

    const int N  = in_sizes[0] / FIN;   // 100000
    const int E  = in_sizes[1] / 2;     // 1600000
    const int nb = (N + BSIZE - 1) >> BSHIFT;   // 782

    char* w = (char*)d_ws;
    uint4* xpack   = (uint4*)w; w += align16((size_t)N * H * 16);   // 22.4 MB
    // shared region: pedge (CSR build) then xhb (proj1->pack1)
    char*  shared  = w;         w += align16((size_t)E * 8 > (size_t)N * HC * 2
                                             ? (size_t)E * 8 : (size_t)N * HC * 2);
    int2*  pedge   = (int2*)shared;
    unsigned short* xhb = (unsigned short*)shared;
    float* aldst   = (float*)w; w += align16((size_t)N * H * 4);    //  5.6 MB
    float* h1      = (float*)w; w += align16((size_t)N * C * 4);    //  2.8 MB
    int*   row_ptr = (int*)w;   w += align16((size_t)(N + 1) * 4);
    int*   col     = (int*)w;   w += align16((size_t)E * 4);        //  6.4 MB
    int*   gcnt    = (int*)w;   w += align16((size_t)nb * 4);
    int*   boff    = (int*)w;   w += align16((size_t)(nb + 1) * 4);
    int*   bcur    = (int*)w;   w += align16((size_t)nb * 4);
    int*   perm    = (int*)w;   w += align16((size_t)N * 4);
    int*   dcnt    = (int*)w;   w += align16(DBINS * 4);
    int*   dcur    = (int*)w;   w += align16(DBINS * 4);
    unsigned short* WtG = (unsigned short*)w; w += align16((size_t)WT_ROWS * FIN * 2);

    const int gAgg  = (N + NPB - 1) / NPB;
    const int gMfma = (N + 63) / 64;
    const int gNH   = (N * H + 255) / 256;
    const int g256N = (N + 255) / 256;

    // ---- bucketed CSR build (no self loops; rebuilt every call) ----
    k_zero<<<(nb + 255) / 256, 256, 0, stream>>>(gcnt, nb);
    k_zero<<<1, 256, 0, stream>>>(dcnt, DBINS);
    k_hist<<<256, 256, 0, stream>>>(ei, E, gcnt, nb);
    k_bscan<<<1, 1024, 0, stream>>>(gcnt, boff, bcur, row_ptr, nb, N);
    k_part<<<256, 256, 0, stream>>>(ei, E, bcur, pedge, nb);
    k_bcsr<<<nb, 256, 0, stream>>>(pedge, boff, row_ptr, col, N);

    // ---- degree-sorted permutation ----
    k_dhist<<<g256N, 256, 0, stream>>>(row_ptr, dcnt, N);
    k_dscan<<<1, 64, 0, stream>>>(dcnt, dcur);
    k_dperm<<<g256N, 256, 0, stream>>>(row_ptr, dcur, perm, N);

    // ---- layer 1 ----
    k_convW<<<(WT_ROWS * FIN + 255) / 256, 256, 0, stream>>>(W1, WtG);
    k_proj1_mfma<<<gMfma, 256, 0, stream>>>(x, WtG, xhb, N);
    k_pack1<<<gNH, 256, 0, stream>>>(xhb, asrc1, adst1, xpack, aldst, N * H);
    k_agg<1><<<gAgg, AGG_BLOCK, 0, stream>>>(perm, row_ptr, col, xpack, aldst, b1,
                                             h1, (float*)d_out, N);
    // ---- layer 2 ----
    k_proj2_pack<<<g256N, 256, 0, stream>>>(h1, W2, asrc2, adst2, xpack, aldst, N);
    k_agg<2><<<gAgg, AGG_BLOCK, 0, stream>>>(perm, row_ptr, col, xpack, aldst, b2,
                                             h1, (float*)d_out, N);
}